// Round 4
// baseline (245.991 us; speedup 1.0000x reference)
//
#include <hip/hip_runtime.h>

#define KAPPA 1.0f

// Native clang vector type: __builtin_nontemporal_load requires a pointer to
// scalar/vector-of-scalar, not HIP_vector_type.
typedef float vfloat4 __attribute__((ext_vector_type(4)));

// Fused kernel: column-sum of [N,256] fp32 -> per-block partials -> last
// block reduces partials and writes loss = -kappa * p0 * ||s||^2.
//
// Column mapping: thread grid-strides float4s with stride % 64 == 0, so each
// thread's float4 accumulator maps to fixed columns (i % 64 invariant). The
// LDS tree reduce uses strides that are multiples of 64 to preserve groups.
__global__ __launch_bounds__(1024) void hub_fused_kernel(
    const float* __restrict__ emb, vfloat4* __restrict__ partial,
    unsigned* __restrict__ counter, const float* __restrict__ p_value,
    float* __restrict__ out, int total_f4, int nb) {
    __shared__ vfloat4 lds[1024];
    __shared__ int last_flag;

    const vfloat4* __restrict__ in = reinterpret_cast<const vfloat4*>(emb);
    vfloat4 acc = (vfloat4)(0.f);

    const int stride = gridDim.x * 1024;
    #pragma unroll 8
    for (int i = blockIdx.x * 1024 + threadIdx.x; i < total_f4; i += stride) {
        vfloat4 v = __builtin_nontemporal_load(&in[i]);
        acc += v;
    }

    lds[threadIdx.x] = acc;
    __syncthreads();

    #pragma unroll
    for (int s = 512; s >= 64; s >>= 1) {
        if (threadIdx.x < (unsigned)s) {
            lds[threadIdx.x] += lds[threadIdx.x + s];
        }
        __syncthreads();
    }

    if (threadIdx.x < 64)
        partial[(size_t)blockIdx.x * 64 + threadIdx.x] = lds[threadIdx.x];

    // Release: make this block's partial stores visible device-wide, then
    // take a ticket. Last block to arrive does the finalize.
    __threadfence();
    __syncthreads();
    if (threadIdx.x == 0)
        last_flag = (atomicAdd(counter, 1u) == (unsigned)(nb - 1));
    __syncthreads();
    if (!last_flag) return;
    __threadfence();  // acquire: see all blocks' partials

    // Finalize: reduce nb*64 float4s (column group i%64 invariant, 1024%64==0).
    vfloat4 facc = (vfloat4)(0.f);
    const int total = nb * 64;
    for (int i = threadIdx.x; i < total; i += 1024) {
        facc += partial[i];
    }
    lds[threadIdx.x] = facc;
    __syncthreads();

    #pragma unroll
    for (int s = 512; s >= 64; s >>= 1) {
        if (threadIdx.x < (unsigned)s) {
            lds[threadIdx.x] += lds[threadIdx.x + s];
        }
        __syncthreads();
    }

    if (threadIdx.x < 64) {
        vfloat4 s4 = lds[threadIdx.x];
        float dotp = s4.x * s4.x + s4.y * s4.y + s4.z * s4.z + s4.w * s4.w;
        #pragma unroll
        for (int off = 32; off > 0; off >>= 1)
            dotp += __shfl_down(dotp, off);
        if (threadIdx.x == 0)
            out[0] = -KAPPA * p_value[0] * dotp;
    }
}

extern "C" void kernel_launch(void* const* d_in, const int* in_sizes, int n_in,
                              void* d_out, int out_size, void* d_ws, size_t ws_size,
                              hipStream_t stream) {
    const float* emb     = (const float*)d_in[0];   // [N, 256] fp32
    const float* p_value = (const float*)d_in[1];   // [1] fp32
    float* out           = (float*)d_out;           // scalar fp32

    const int n_elems  = in_sizes[0];               // N * 256
    const int total_f4 = n_elems / 4;               // float4 count

    int nb = 512;                                   // 1 KiB partials per block
    size_t part_bytes = (size_t)nb * 64 * sizeof(vfloat4);  // 512 KiB
    if (part_bytes + sizeof(unsigned) > ws_size) {
        nb = (int)((ws_size - sizeof(unsigned)) / (64 * sizeof(vfloat4)));
        if (nb < 1) nb = 1;
        part_bytes = (size_t)nb * 64 * sizeof(vfloat4);
    }

    vfloat4* partial  = (vfloat4*)d_ws;
    unsigned* counter = (unsigned*)((char*)d_ws + part_bytes);

    // Zero the ticket counter (graph-capturable async memset; deterministic).
    (void)hipMemsetAsync(counter, 0, sizeof(unsigned), stream);

    hub_fused_kernel<<<nb, 1024, 0, stream>>>(emb, partial, counter, p_value,
                                              out, total_f4, nb);
}

// Round 5
// 221.699 us; speedup vs baseline: 1.1096x; 1.1096x over previous
//
#include <hip/hip_runtime.h>

#define KAPPA 1.0f

typedef float vfloat4 __attribute__((ext_vector_type(4)));

// Fused kernel: column-sum of [N,256] fp32 -> per-block partials -> last
// block reduces partials and writes loss = -kappa * p0 * ||s||^2.
//
// Column mapping: thread grid-strides float4s with stride % 64 == 0, so each
// thread's float4 accumulator maps to fixed columns (i % 64 invariant). The
// LDS tree reduce uses strides that are multiples of 64 to preserve groups.
//
// NOTE (r4 post-mortem): __builtin_nontemporal_load regressed 57->246us here:
// nt flag defeats L2/L3 AND blocks compiler load pipelining (VGPR=20, ~1 load
// in flight, 500 GB/s). Plain cached loads restore deep MLP.
__global__ __launch_bounds__(1024) void hub_fused_kernel(
    const float* __restrict__ emb, vfloat4* __restrict__ partial,
    unsigned* __restrict__ counter, const float* __restrict__ p_value,
    float* __restrict__ out, int total_f4, int nb) {
    __shared__ vfloat4 lds[1024];
    __shared__ int last_flag;

    const vfloat4* __restrict__ in = reinterpret_cast<const vfloat4*>(emb);
    vfloat4 acc = (vfloat4)(0.f);

    const int stride = gridDim.x * 1024;
    #pragma unroll 8
    for (int i = blockIdx.x * 1024 + threadIdx.x; i < total_f4; i += stride) {
        acc += in[i];
    }

    lds[threadIdx.x] = acc;
    __syncthreads();

    #pragma unroll
    for (int s = 512; s >= 64; s >>= 1) {
        if (threadIdx.x < (unsigned)s) {
            lds[threadIdx.x] += lds[threadIdx.x + s];
        }
        __syncthreads();
    }

    if (threadIdx.x < 64)
        partial[(size_t)blockIdx.x * 64 + threadIdx.x] = lds[threadIdx.x];

    // Release: make this block's partial stores visible device-wide, then
    // take a ticket. Last block to arrive does the finalize.
    __threadfence();
    __syncthreads();
    if (threadIdx.x == 0)
        last_flag = (atomicAdd(counter, 1u) == (unsigned)(nb - 1));
    __syncthreads();
    if (!last_flag) return;
    __threadfence();  // acquire: see all blocks' partials

    // Finalize: reduce nb*64 float4s (column group i%64 invariant, 1024%64==0).
    vfloat4 facc = (vfloat4)(0.f);
    const int total = nb * 64;
    for (int i = threadIdx.x; i < total; i += 1024) {
        facc += partial[i];
    }
    lds[threadIdx.x] = facc;
    __syncthreads();

    #pragma unroll
    for (int s = 512; s >= 64; s >>= 1) {
        if (threadIdx.x < (unsigned)s) {
            lds[threadIdx.x] += lds[threadIdx.x + s];
        }
        __syncthreads();
    }

    if (threadIdx.x < 64) {
        vfloat4 s4 = lds[threadIdx.x];
        float dotp = s4.x * s4.x + s4.y * s4.y + s4.z * s4.z + s4.w * s4.w;
        #pragma unroll
        for (int off = 32; off > 0; off >>= 1)
            dotp += __shfl_down(dotp, off);
        if (threadIdx.x == 0)
            out[0] = -KAPPA * p_value[0] * dotp;
    }
}

extern "C" void kernel_launch(void* const* d_in, const int* in_sizes, int n_in,
                              void* d_out, int out_size, void* d_ws, size_t ws_size,
                              hipStream_t stream) {
    const float* emb     = (const float*)d_in[0];   // [N, 256] fp32
    const float* p_value = (const float*)d_in[1];   // [1] fp32
    float* out           = (float*)d_out;           // scalar fp32

    const int n_elems  = in_sizes[0];               // N * 256
    const int total_f4 = n_elems / 4;               // float4 count

    int nb = 512;                                   // 1 KiB partials per block
    size_t part_bytes = (size_t)nb * 64 * sizeof(vfloat4);  // 512 KiB
    if (part_bytes + sizeof(unsigned) > ws_size) {
        nb = (int)((ws_size - sizeof(unsigned)) / (64 * sizeof(vfloat4)));
        if (nb < 1) nb = 1;
        part_bytes = (size_t)nb * 64 * sizeof(vfloat4);
    }

    vfloat4* partial  = (vfloat4*)d_ws;
    unsigned* counter = (unsigned*)((char*)d_ws + part_bytes);

    // Zero the ticket counter (graph-capturable async memset; deterministic).
    (void)hipMemsetAsync(counter, 0, sizeof(unsigned), stream);

    hub_fused_kernel<<<nb, 1024, 0, stream>>>(emb, partial, counter, p_value,
                                              out, total_f4, nb);
}

// Round 6
// 56.560 us; speedup vs baseline: 4.3492x; 3.9197x over previous
//
#include <hip/hip_runtime.h>

#define KAPPA 1.0f

// Two-kernel structure ON PURPOSE (r5 post-mortem): a fused single-kernel
// version with __threadfence()+atomic ticket ran 4x SLOWER (222us vs 57us) --
// device-scope fences on gfx950 flush/invalidate per-XCD L2s while other
// blocks still stream, serializing the TCC pipe (VALUBusy 0.7%, 450 GB/s).
// The kernel-launch boundary is the cheap device-wide fence.

// Kernel 1: column-sum of [N, 256] fp32 matrix into per-block partials.
// Each thread grid-strides over float4 elements; since the stride is a
// multiple of 64 (float4s per row), each thread's accumulator maps to a
// fixed group of 4 columns (i % 64 invariant).
__global__ __launch_bounds__(1024) void hub_colsum_kernel(
    const float* __restrict__ emb, float4* __restrict__ partial, int total_f4) {
    __shared__ float4 lds[1024];

    const float4* __restrict__ in = reinterpret_cast<const float4*>(emb);
    float4 acc = make_float4(0.f, 0.f, 0.f, 0.f);

    const int stride = gridDim.x * blockDim.x;
    #pragma unroll 8
    for (int i = blockIdx.x * blockDim.x + threadIdx.x; i < total_f4; i += stride) {
        float4 v = in[i];
        acc.x += v.x; acc.y += v.y; acc.z += v.z; acc.w += v.w;
    }

    lds[threadIdx.x] = acc;
    __syncthreads();

    // Tree reduce: strides 512,256,128,64 are all multiples of 64, so
    // combined threads share the same column group.
    #pragma unroll
    for (int s = 512; s >= 64; s >>= 1) {
        if (threadIdx.x < (unsigned)s) {
            float4 o = lds[threadIdx.x + s];
            float4 m = lds[threadIdx.x];
            m.x += o.x; m.y += o.y; m.z += o.z; m.w += o.w;
            lds[threadIdx.x] = m;
        }
        __syncthreads();
    }

    if (threadIdx.x < 64) {
        // Row-major partials: partial[block][64 float4s] = 256 columns.
        partial[(size_t)blockIdx.x * 64 + threadIdx.x] = lds[threadIdx.x];
    }
}

// Kernel 2: reduce nb partial rows (nb x 64 float4s), then loss = -kappa*p0*dot(s,s).
// 1024 threads: nb*64/1024 iterations, column group (i % 64) invariant since
// 1024 % 64 == 0.
__global__ __launch_bounds__(1024) void hub_finalize_kernel(
    const float4* __restrict__ partial, const float* __restrict__ p_value,
    float* __restrict__ out, int nb) {
    __shared__ float4 lds[1024];

    float4 acc = make_float4(0.f, 0.f, 0.f, 0.f);
    const int total = nb * 64;
    for (int i = threadIdx.x; i < total; i += 1024) {
        float4 v = partial[i];
        acc.x += v.x; acc.y += v.y; acc.z += v.z; acc.w += v.w;
    }
    lds[threadIdx.x] = acc;
    __syncthreads();

    // Tree reduce down to 64 entries (one full set of 256 columns).
    #pragma unroll
    for (int s = 512; s >= 64; s >>= 1) {
        if (threadIdx.x < (unsigned)s) {
            float4 o = lds[threadIdx.x + s];
            float4 m = lds[threadIdx.x];
            m.x += o.x; m.y += o.y; m.z += o.z; m.w += o.w;
            lds[threadIdx.x] = m;
        }
        __syncthreads();
    }

    if (threadIdx.x < 64) {
        float4 s4 = lds[threadIdx.x];
        float dotp = s4.x * s4.x + s4.y * s4.y + s4.z * s4.z + s4.w * s4.w;

        // Wave-level reduce across the 64 lanes of wave 0 (all active).
        #pragma unroll
        for (int off = 32; off > 0; off >>= 1)
            dotp += __shfl_down(dotp, off);

        if (threadIdx.x == 0)
            out[0] = -KAPPA * p_value[0] * dotp;
    }
}

extern "C" void kernel_launch(void* const* d_in, const int* in_sizes, int n_in,
                              void* d_out, int out_size, void* d_ws, size_t ws_size,
                              hipStream_t stream) {
    const float* emb     = (const float*)d_in[0];   // [N, 256] fp32
    const float* p_value = (const float*)d_in[1];   // [1] fp32
    float* out           = (float*)d_out;           // scalar fp32

    const int n_elems  = in_sizes[0];               // N * 256
    const int total_f4 = n_elems / 4;               // float4 count

    // 512 blocks x 1024 threads = exactly 2 blocks/CU on 256 CUs, no tail.
    int nb = 512;
    size_t need_per_block = 64 * sizeof(float4);    // 1024 B
    if ((size_t)nb * need_per_block > ws_size) {
        nb = (int)(ws_size / need_per_block);
        if (nb < 1) nb = 1;
    }

    float4* partial = (float4*)d_ws;

    hub_colsum_kernel<<<nb, 1024, 0, stream>>>(emb, partial, total_f4);
    hub_finalize_kernel<<<1, 1024, 0, stream>>>(partial, p_value, out, nb);
}

// Round 7
// 52.320 us; speedup vs baseline: 4.7016x; 1.0810x over previous
//
#include <hip/hip_runtime.h>

#define KAPPA 1.0f

// Two-kernel structure ON PURPOSE (r5 post-mortem): fused single-kernel with
// __threadfence()+atomic ticket ran 4x SLOWER (222us vs 57us) -- device-scope
// fences on gfx950 flush per-XCD L2s mid-stream, serializing the TCC pipe.
// The kernel-launch boundary is the cheap device-wide fence.
//
// r6 post-mortem: #pragma unroll alone leaves VGPR=20 (~3 loads in flight;
// compiler register-thrifts and serializes load->add->reuse). This version
// forces 8 named loads issued before any use, so >=32 data VGPRs and 8
// outstanding global_load_dwordx4 per wave.

// Kernel 1: column-sum of [N, 256] fp32 into per-block partials.
// Grid-stride by BATCH*stride; stride % 64 == 0 so each thread's accumulator
// maps to a fixed group of 4 columns (i % 64 invariant).
__global__ __launch_bounds__(1024) void hub_colsum_kernel(
    const float* __restrict__ emb, float4* __restrict__ partial, int total_f4) {
    __shared__ float4 lds[1024];

    const float4* __restrict__ in = reinterpret_cast<const float4*>(emb);
    float4 acc = make_float4(0.f, 0.f, 0.f, 0.f);

    const int stride = gridDim.x * 1024;          // float4s per grid pass
    const int tid    = blockIdx.x * 1024 + threadIdx.x;

    // Main path: batches of 8 grid passes. total_f4 = 16777216, stride =
    // 512*1024 = 524288 -> exactly 32 passes = 4 full batches, no tail (but
    // keep a tail loop for safety on other sizes).
    int i = tid;
    for (; i + 7 * stride < total_f4; i += 8 * stride) {
        float4 v0 = in[i + 0 * stride];
        float4 v1 = in[i + 1 * stride];
        float4 v2 = in[i + 2 * stride];
        float4 v3 = in[i + 3 * stride];
        float4 v4 = in[i + 4 * stride];
        float4 v5 = in[i + 5 * stride];
        float4 v6 = in[i + 6 * stride];
        float4 v7 = in[i + 7 * stride];
        acc.x += v0.x; acc.y += v0.y; acc.z += v0.z; acc.w += v0.w;
        acc.x += v1.x; acc.y += v1.y; acc.z += v1.z; acc.w += v1.w;
        acc.x += v2.x; acc.y += v2.y; acc.z += v2.z; acc.w += v2.w;
        acc.x += v3.x; acc.y += v3.y; acc.z += v3.z; acc.w += v3.w;
        acc.x += v4.x; acc.y += v4.y; acc.z += v4.z; acc.w += v4.w;
        acc.x += v5.x; acc.y += v5.y; acc.z += v5.z; acc.w += v5.w;
        acc.x += v6.x; acc.y += v6.y; acc.z += v6.z; acc.w += v6.w;
        acc.x += v7.x; acc.y += v7.y; acc.z += v7.z; acc.w += v7.w;
    }
    for (; i < total_f4; i += stride) {
        float4 v = in[i];
        acc.x += v.x; acc.y += v.y; acc.z += v.z; acc.w += v.w;
    }

    lds[threadIdx.x] = acc;
    __syncthreads();

    // Tree reduce: strides 512..64 are multiples of 64 -> column groups align.
    #pragma unroll
    for (int s = 512; s >= 64; s >>= 1) {
        if (threadIdx.x < (unsigned)s) {
            float4 o = lds[threadIdx.x + s];
            float4 m = lds[threadIdx.x];
            m.x += o.x; m.y += o.y; m.z += o.z; m.w += o.w;
            lds[threadIdx.x] = m;
        }
        __syncthreads();
    }

    if (threadIdx.x < 64)
        partial[(size_t)blockIdx.x * 64 + threadIdx.x] = lds[threadIdx.x];
}

// Kernel 2: reduce nb x 64 float4 partials, then loss = -kappa*p0*dot(s,s).
// Single block, latency-bound on ~512 KB from L3 -> force 8 loads in flight.
__global__ __launch_bounds__(1024) void hub_finalize_kernel(
    const float4* __restrict__ partial, const float* __restrict__ p_value,
    float* __restrict__ out, int nb) {
    __shared__ float4 lds[1024];

    float4 acc = make_float4(0.f, 0.f, 0.f, 0.f);
    const int total = nb * 64;                    // 32768 for nb=512

    int i = threadIdx.x;
    for (; i + 7 * 1024 < total; i += 8 * 1024) {
        float4 v0 = partial[i + 0 * 1024];
        float4 v1 = partial[i + 1 * 1024];
        float4 v2 = partial[i + 2 * 1024];
        float4 v3 = partial[i + 3 * 1024];
        float4 v4 = partial[i + 4 * 1024];
        float4 v5 = partial[i + 5 * 1024];
        float4 v6 = partial[i + 6 * 1024];
        float4 v7 = partial[i + 7 * 1024];
        acc.x += v0.x; acc.y += v0.y; acc.z += v0.z; acc.w += v0.w;
        acc.x += v1.x; acc.y += v1.y; acc.z += v1.z; acc.w += v1.w;
        acc.x += v2.x; acc.y += v2.y; acc.z += v2.z; acc.w += v2.w;
        acc.x += v3.x; acc.y += v3.y; acc.z += v3.z; acc.w += v3.w;
        acc.x += v4.x; acc.y += v4.y; acc.z += v4.z; acc.w += v4.w;
        acc.x += v5.x; acc.y += v5.y; acc.z += v5.z; acc.w += v5.w;
        acc.x += v6.x; acc.y += v6.y; acc.z += v6.z; acc.w += v6.w;
        acc.x += v7.x; acc.y += v7.y; acc.z += v7.z; acc.w += v7.w;
    }
    for (; i < total; i += 1024) {
        float4 v = partial[i];
        acc.x += v.x; acc.y += v.y; acc.z += v.z; acc.w += v.w;
    }

    lds[threadIdx.x] = acc;
    __syncthreads();

    #pragma unroll
    for (int s = 512; s >= 64; s >>= 1) {
        if (threadIdx.x < (unsigned)s) {
            float4 o = lds[threadIdx.x + s];
            float4 m = lds[threadIdx.x];
            m.x += o.x; m.y += o.y; m.z += o.z; m.w += o.w;
            lds[threadIdx.x] = m;
        }
        __syncthreads();
    }

    if (threadIdx.x < 64) {
        float4 s4 = lds[threadIdx.x];
        float dotp = s4.x * s4.x + s4.y * s4.y + s4.z * s4.z + s4.w * s4.w;
        #pragma unroll
        for (int off = 32; off > 0; off >>= 1)
            dotp += __shfl_down(dotp, off);
        if (threadIdx.x == 0)
            out[0] = -KAPPA * p_value[0] * dotp;
    }
}

extern "C" void kernel_launch(void* const* d_in, const int* in_sizes, int n_in,
                              void* d_out, int out_size, void* d_ws, size_t ws_size,
                              hipStream_t stream) {
    const float* emb     = (const float*)d_in[0];   // [N, 256] fp32
    const float* p_value = (const float*)d_in[1];   // [1] fp32
    float* out           = (float*)d_out;           // scalar fp32

    const int n_elems  = in_sizes[0];               // N * 256
    const int total_f4 = n_elems / 4;               // float4 count

    // 512 blocks x 1024 threads = exactly 2 blocks/CU on 256 CUs, no tail.
    int nb = 512;
    size_t need_per_block = 64 * sizeof(float4);    // 1024 B
    if ((size_t)nb * need_per_block > ws_size) {
        nb = (int)(ws_size / need_per_block);
        if (nb < 1) nb = 1;
    }

    float4* partial = (float4*)d_ws;

    hub_colsum_kernel<<<nb, 1024, 0, stream>>>(emb, partial, total_f4);
    hub_finalize_kernel<<<1, 1024, 0, stream>>>(partial, p_value, out, nb);
}

// Round 8
// 51.170 us; speedup vs baseline: 4.8073x; 1.0225x over previous
//
#include <hip/hip_runtime.h>

#define KAPPA 1.0f

// Two-kernel structure ON PURPOSE (r5 post-mortem): fused single-kernel with
// __threadfence()+atomic ticket ran 4x SLOWER (222us vs 57us) -- device-scope
// fences on gfx950 flush per-XCD L2s mid-stream, serializing the TCC pipe.
// The kernel-launch boundary is the cheap device-wide fence.
//
// r6/r7: #pragma unroll leaves VGPR=20 (~3 loads in flight); explicit named
// 8-deep load batches restored MLP (56.6 -> 52.3us). This round: 16-deep
// batches in k2 + single-barrier LDS reduce (1 barrier instead of 5).

// Kernel 1: column-sum of [N, 256] fp32 into per-block partials.
// stride % 64 == 0 so each thread's accumulator maps to a fixed group of 4
// columns (i % 64 invariant); lds[j] holds column group j % 64.
__global__ __launch_bounds__(1024) void hub_colsum_kernel(
    const float* __restrict__ emb, float4* __restrict__ partial, int total_f4) {
    __shared__ float4 lds[1024];

    const float4* __restrict__ in = reinterpret_cast<const float4*>(emb);
    float4 acc = make_float4(0.f, 0.f, 0.f, 0.f);

    const int stride = gridDim.x * 1024;          // float4s per grid pass
    const int tid    = blockIdx.x * 1024 + threadIdx.x;

    // 8-deep explicit load batches: 8 outstanding global_load_dwordx4/wave.
    int i = tid;
    for (; i + 7 * stride < total_f4; i += 8 * stride) {
        float4 v0 = in[i + 0 * stride];
        float4 v1 = in[i + 1 * stride];
        float4 v2 = in[i + 2 * stride];
        float4 v3 = in[i + 3 * stride];
        float4 v4 = in[i + 4 * stride];
        float4 v5 = in[i + 5 * stride];
        float4 v6 = in[i + 6 * stride];
        float4 v7 = in[i + 7 * stride];
        acc.x += v0.x; acc.y += v0.y; acc.z += v0.z; acc.w += v0.w;
        acc.x += v1.x; acc.y += v1.y; acc.z += v1.z; acc.w += v1.w;
        acc.x += v2.x; acc.y += v2.y; acc.z += v2.z; acc.w += v2.w;
        acc.x += v3.x; acc.y += v3.y; acc.z += v3.z; acc.w += v3.w;
        acc.x += v4.x; acc.y += v4.y; acc.z += v4.z; acc.w += v4.w;
        acc.x += v5.x; acc.y += v5.y; acc.z += v5.z; acc.w += v5.w;
        acc.x += v6.x; acc.y += v6.y; acc.z += v6.z; acc.w += v6.w;
        acc.x += v7.x; acc.y += v7.y; acc.z += v7.z; acc.w += v7.w;
    }
    for (; i < total_f4; i += stride) {
        float4 v = in[i];
        acc.x += v.x; acc.y += v.y; acc.z += v.z; acc.w += v.w;
    }

    lds[threadIdx.x] = acc;
    __syncthreads();

    // Single-barrier reduce: wave 0 sums the 16 stride-64 entries of its
    // column group (16 ds_read_b128; 8-way bank alias is trivial at this
    // op count) -- replaces a 5-barrier tree.
    if (threadIdx.x < 64) {
        float4 m = lds[threadIdx.x];
        #pragma unroll
        for (int k = 1; k < 16; ++k) {
            float4 o = lds[threadIdx.x + 64 * k];
            m.x += o.x; m.y += o.y; m.z += o.z; m.w += o.w;
        }
        partial[(size_t)blockIdx.x * 64 + threadIdx.x] = m;
    }
}

// Kernel 2: reduce nb x 64 float4 partials, then loss = -kappa*p0*dot(s,s).
// Single block; 16-deep load batches (2 dependent rounds over 512 KB).
__global__ __launch_bounds__(1024) void hub_finalize_kernel(
    const float4* __restrict__ partial, const float* __restrict__ p_value,
    float* __restrict__ out, int nb) {
    __shared__ float4 lds[1024];

    float4 acc = make_float4(0.f, 0.f, 0.f, 0.f);
    const int total = nb * 64;                    // 32768 for nb=512

    int i = threadIdx.x;
    for (; i + 15 * 1024 < total; i += 16 * 1024) {
        float4 v0  = partial[i +  0 * 1024];
        float4 v1  = partial[i +  1 * 1024];
        float4 v2  = partial[i +  2 * 1024];
        float4 v3  = partial[i +  3 * 1024];
        float4 v4  = partial[i +  4 * 1024];
        float4 v5  = partial[i +  5 * 1024];
        float4 v6  = partial[i +  6 * 1024];
        float4 v7  = partial[i +  7 * 1024];
        float4 v8  = partial[i +  8 * 1024];
        float4 v9  = partial[i +  9 * 1024];
        float4 v10 = partial[i + 10 * 1024];
        float4 v11 = partial[i + 11 * 1024];
        float4 v12 = partial[i + 12 * 1024];
        float4 v13 = partial[i + 13 * 1024];
        float4 v14 = partial[i + 14 * 1024];
        float4 v15 = partial[i + 15 * 1024];
        acc.x += v0.x;  acc.y += v0.y;  acc.z += v0.z;  acc.w += v0.w;
        acc.x += v1.x;  acc.y += v1.y;  acc.z += v1.z;  acc.w += v1.w;
        acc.x += v2.x;  acc.y += v2.y;  acc.z += v2.z;  acc.w += v2.w;
        acc.x += v3.x;  acc.y += v3.y;  acc.z += v3.z;  acc.w += v3.w;
        acc.x += v4.x;  acc.y += v4.y;  acc.z += v4.z;  acc.w += v4.w;
        acc.x += v5.x;  acc.y += v5.y;  acc.z += v5.z;  acc.w += v5.w;
        acc.x += v6.x;  acc.y += v6.y;  acc.z += v6.z;  acc.w += v6.w;
        acc.x += v7.x;  acc.y += v7.y;  acc.z += v7.z;  acc.w += v7.w;
        acc.x += v8.x;  acc.y += v8.y;  acc.z += v8.z;  acc.w += v8.w;
        acc.x += v9.x;  acc.y += v9.y;  acc.z += v9.z;  acc.w += v9.w;
        acc.x += v10.x; acc.y += v10.y; acc.z += v10.z; acc.w += v10.w;
        acc.x += v11.x; acc.y += v11.y; acc.z += v11.z; acc.w += v11.w;
        acc.x += v12.x; acc.y += v12.y; acc.z += v12.z; acc.w += v12.w;
        acc.x += v13.x; acc.y += v13.y; acc.z += v13.z; acc.w += v13.w;
        acc.x += v14.x; acc.y += v14.y; acc.z += v14.z; acc.w += v14.w;
        acc.x += v15.x; acc.y += v15.y; acc.z += v15.z; acc.w += v15.w;
    }
    for (; i < total; i += 1024) {
        float4 v = partial[i];
        acc.x += v.x; acc.y += v.y; acc.z += v.z; acc.w += v.w;
    }

    lds[threadIdx.x] = acc;
    __syncthreads();

    // Single-barrier reduce to the 64 column-group sums, then dot + shuffle.
    if (threadIdx.x < 64) {
        float4 m = lds[threadIdx.x];
        #pragma unroll
        for (int k = 1; k < 16; ++k) {
            float4 o = lds[threadIdx.x + 64 * k];
            m.x += o.x; m.y += o.y; m.z += o.z; m.w += o.w;
        }
        float dotp = m.x * m.x + m.y * m.y + m.z * m.z + m.w * m.w;
        #pragma unroll
        for (int off = 32; off > 0; off >>= 1)
            dotp += __shfl_down(dotp, off);
        if (threadIdx.x == 0)
            out[0] = -KAPPA * p_value[0] * dotp;
    }
}

extern "C" void kernel_launch(void* const* d_in, const int* in_sizes, int n_in,
                              void* d_out, int out_size, void* d_ws, size_t ws_size,
                              hipStream_t stream) {
    const float* emb     = (const float*)d_in[0];   // [N, 256] fp32
    const float* p_value = (const float*)d_in[1];   // [1] fp32
    float* out           = (float*)d_out;           // scalar fp32

    const int n_elems  = in_sizes[0];               // N * 256
    const int total_f4 = n_elems / 4;               // float4 count

    // 512 blocks x 1024 threads = exactly 2 blocks/CU on 256 CUs, no tail.
    int nb = 512;
    size_t need_per_block = 64 * sizeof(float4);    // 1024 B
    if ((size_t)nb * need_per_block > ws_size) {
        nb = (int)(ws_size / need_per_block);
        if (nb < 1) nb = 1;
    }

    float4* partial = (float4*)d_ws;

    hub_colsum_kernel<<<nb, 1024, 0, stream>>>(emb, partial, total_f4);
    hub_finalize_kernel<<<1, 1024, 0, stream>>>(partial, p_value, out, nb);
}

// Round 9
// 48.953 us; speedup vs baseline: 5.0250x; 1.0453x over previous
//
#include <hip/hip_runtime.h>

#define KAPPA 1.0f

// Two-kernel structure ON PURPOSE (r5 post-mortem): fused single-kernel with
// __threadfence()+atomic ticket ran 4x SLOWER (222us vs 57us) -- device-scope
// fences on gfx950 flush per-XCD L2s mid-stream, serializing the TCC pipe.
// The kernel-launch boundary is the cheap device-wide fence.
//
// r6/r7: #pragma unroll leaves VGPR=20 (~3 loads in flight); explicit named
// 8-deep load batches restored MLP (56.6 -> 52.3us). r8: single-barrier LDS
// reduce + 16-deep k2 batches (-1.1us). r9: nb 512->256 (1 block/CU) halves
// the partial buffer k2 must chew through.

// Kernel 1: column-sum of [N, 256] fp32 into per-block partials.
// stride % 64 == 0 so each thread's accumulator maps to a fixed group of 4
// columns (i % 64 invariant); lds[j] holds column group j % 64.
__global__ __launch_bounds__(1024) void hub_colsum_kernel(
    const float* __restrict__ emb, float4* __restrict__ partial, int total_f4) {
    __shared__ float4 lds[1024];

    const float4* __restrict__ in = reinterpret_cast<const float4*>(emb);
    float4 acc = make_float4(0.f, 0.f, 0.f, 0.f);

    const int stride = gridDim.x * 1024;          // float4s per grid pass
    const int tid    = blockIdx.x * 1024 + threadIdx.x;

    // 8-deep explicit load batches: 8 outstanding global_load_dwordx4/wave.
    int i = tid;
    for (; i + 7 * stride < total_f4; i += 8 * stride) {
        float4 v0 = in[i + 0 * stride];
        float4 v1 = in[i + 1 * stride];
        float4 v2 = in[i + 2 * stride];
        float4 v3 = in[i + 3 * stride];
        float4 v4 = in[i + 4 * stride];
        float4 v5 = in[i + 5 * stride];
        float4 v6 = in[i + 6 * stride];
        float4 v7 = in[i + 7 * stride];
        acc.x += v0.x; acc.y += v0.y; acc.z += v0.z; acc.w += v0.w;
        acc.x += v1.x; acc.y += v1.y; acc.z += v1.z; acc.w += v1.w;
        acc.x += v2.x; acc.y += v2.y; acc.z += v2.z; acc.w += v2.w;
        acc.x += v3.x; acc.y += v3.y; acc.z += v3.z; acc.w += v3.w;
        acc.x += v4.x; acc.y += v4.y; acc.z += v4.z; acc.w += v4.w;
        acc.x += v5.x; acc.y += v5.y; acc.z += v5.z; acc.w += v5.w;
        acc.x += v6.x; acc.y += v6.y; acc.z += v6.z; acc.w += v6.w;
        acc.x += v7.x; acc.y += v7.y; acc.z += v7.z; acc.w += v7.w;
    }
    for (; i < total_f4; i += stride) {
        float4 v = in[i];
        acc.x += v.x; acc.y += v.y; acc.z += v.z; acc.w += v.w;
    }

    lds[threadIdx.x] = acc;
    __syncthreads();

    // Single-barrier reduce: wave 0 sums the 16 stride-64 entries of its
    // column group (16 ds_read_b128) -- replaces a 5-barrier tree.
    if (threadIdx.x < 64) {
        float4 m = lds[threadIdx.x];
        #pragma unroll
        for (int k = 1; k < 16; ++k) {
            float4 o = lds[threadIdx.x + 64 * k];
            m.x += o.x; m.y += o.y; m.z += o.z; m.w += o.w;
        }
        partial[(size_t)blockIdx.x * 64 + threadIdx.x] = m;
    }
}

// Kernel 2: reduce nb x 64 float4 partials, then loss = -kappa*p0*dot(s,s).
// Single block; 16-deep load batches. With nb=256 the whole read is one
// batch per thread (16384 float4s = 256 KB).
__global__ __launch_bounds__(1024) void hub_finalize_kernel(
    const float4* __restrict__ partial, const float* __restrict__ p_value,
    float* __restrict__ out, int nb) {
    __shared__ float4 lds[1024];

    float4 acc = make_float4(0.f, 0.f, 0.f, 0.f);
    const int total = nb * 64;                    // 16384 for nb=256

    int i = threadIdx.x;
    for (; i + 15 * 1024 < total; i += 16 * 1024) {
        float4 v0  = partial[i +  0 * 1024];
        float4 v1  = partial[i +  1 * 1024];
        float4 v2  = partial[i +  2 * 1024];
        float4 v3  = partial[i +  3 * 1024];
        float4 v4  = partial[i +  4 * 1024];
        float4 v5  = partial[i +  5 * 1024];
        float4 v6  = partial[i +  6 * 1024];
        float4 v7  = partial[i +  7 * 1024];
        float4 v8  = partial[i +  8 * 1024];
        float4 v9  = partial[i +  9 * 1024];
        float4 v10 = partial[i + 10 * 1024];
        float4 v11 = partial[i + 11 * 1024];
        float4 v12 = partial[i + 12 * 1024];
        float4 v13 = partial[i + 13 * 1024];
        float4 v14 = partial[i + 14 * 1024];
        float4 v15 = partial[i + 15 * 1024];
        acc.x += v0.x;  acc.y += v0.y;  acc.z += v0.z;  acc.w += v0.w;
        acc.x += v1.x;  acc.y += v1.y;  acc.z += v1.z;  acc.w += v1.w;
        acc.x += v2.x;  acc.y += v2.y;  acc.z += v2.z;  acc.w += v2.w;
        acc.x += v3.x;  acc.y += v3.y;  acc.z += v3.z;  acc.w += v3.w;
        acc.x += v4.x;  acc.y += v4.y;  acc.z += v4.z;  acc.w += v4.w;
        acc.x += v5.x;  acc.y += v5.y;  acc.z += v5.z;  acc.w += v5.w;
        acc.x += v6.x;  acc.y += v6.y;  acc.z += v6.z;  acc.w += v6.w;
        acc.x += v7.x;  acc.y += v7.y;  acc.z += v7.z;  acc.w += v7.w;
        acc.x += v8.x;  acc.y += v8.y;  acc.z += v8.z;  acc.w += v8.w;
        acc.x += v9.x;  acc.y += v9.y;  acc.z += v9.z;  acc.w += v9.w;
        acc.x += v10.x; acc.y += v10.y; acc.z += v10.z; acc.w += v10.w;
        acc.x += v11.x; acc.y += v11.y; acc.z += v11.z; acc.w += v11.w;
        acc.x += v12.x; acc.y += v12.y; acc.z += v12.z; acc.w += v12.w;
        acc.x += v13.x; acc.y += v13.y; acc.z += v13.z; acc.w += v13.w;
        acc.x += v14.x; acc.y += v14.y; acc.z += v14.z; acc.w += v14.w;
        acc.x += v15.x; acc.y += v15.y; acc.z += v15.z; acc.w += v15.w;
    }
    for (; i < total; i += 1024) {
        float4 v = partial[i];
        acc.x += v.x; acc.y += v.y; acc.z += v.z; acc.w += v.w;
    }

    lds[threadIdx.x] = acc;
    __syncthreads();

    // Single-barrier reduce to the 64 column-group sums, then dot + shuffle.
    if (threadIdx.x < 64) {
        float4 m = lds[threadIdx.x];
        #pragma unroll
        for (int k = 1; k < 16; ++k) {
            float4 o = lds[threadIdx.x + 64 * k];
            m.x += o.x; m.y += o.y; m.z += o.z; m.w += o.w;
        }
        float dotp = m.x * m.x + m.y * m.y + m.z * m.z + m.w * m.w;
        #pragma unroll
        for (int off = 32; off > 0; off >>= 1)
            dotp += __shfl_down(dotp, off);
        if (threadIdx.x == 0)
            out[0] = -KAPPA * p_value[0] * dotp;
    }
}

extern "C" void kernel_launch(void* const* d_in, const int* in_sizes, int n_in,
                              void* d_out, int out_size, void* d_ws, size_t ws_size,
                              hipStream_t stream) {
    const float* emb     = (const float*)d_in[0];   // [N, 256] fp32
    const float* p_value = (const float*)d_in[1];   // [1] fp32
    float* out           = (float*)d_out;           // scalar fp32

    const int n_elems  = in_sizes[0];               // N * 256
    const int total_f4 = n_elems / 4;               // float4 count

    // 256 blocks x 1024 threads = 1 block/CU; halves the partial buffer k2
    // reads (256 KB) while keeping 128 KB of loads in flight per CU.
    int nb = 256;
    size_t need_per_block = 64 * sizeof(float4);    // 1024 B
    if ((size_t)nb * need_per_block > ws_size) {
        nb = (int)(ws_size / need_per_block);
        if (nb < 1) nb = 1;
    }

    float4* partial = (float4*)d_ws;

    hub_colsum_kernel<<<nb, 1024, 0, stream>>>(emb, partial, total_f4);
    hub_finalize_kernel<<<1, 1024, 0, stream>>>(partial, p_value, out, nb);
}